// Round 11
// baseline (232.214 us; speedup 1.0000x reference)
//
#include <hip/hip_runtime.h>

typedef unsigned short u16;
typedef __attribute__((ext_vector_type(8))) short bf16x8;
typedef __attribute__((ext_vector_type(4))) float f32x4;
typedef __attribute__((ext_vector_type(4))) int   i32x4;
typedef __attribute__((ext_vector_type(4))) unsigned short u16x4;

#define DM 1024

__device__ __forceinline__ float bf2f(u16 u){
  union { unsigned int i; float f; } v; v.i = ((unsigned int)u)<<16; return v.f;
}
__device__ __forceinline__ u16 f2bf(float f){
  unsigned int x = __float_as_uint(f);
  return (u16)((x + 0x7FFFu + ((x>>16)&1u)) >> 16);   // RNE, finite inputs only
}

// ---------------- K0: fused weight-quantize (blocks 0..1023) + x->bf16 (rest) -------
// wq (bf16) rows: [0,1024) = R ; [1024,3072) = K[d],V[d] interleaved.
// wq8 (i8)  rows: [0,1024) = O (ternary exact in i8).  wsc: all 4096 rows.
__global__ __launch_bounds__(256)
void init_pack(const float* __restrict__ W0, const float* __restrict__ W1,
               const float* __restrict__ W2, const float* __restrict__ W3,
               const float* __restrict__ x,
               u16* __restrict__ wq, signed char* __restrict__ wq8,
               float* __restrict__ wsc, u16* __restrict__ xb)
{
  if (blockIdx.x >= 1024){                     // ---- x f32 -> bf16 ----
    const int i = ((blockIdx.x-1024)*256 + threadIdx.x)*4;
    float4 v = *(const float4*)&x[i];
    u16x4 o; o[0]=f2bf(v.x); o[1]=f2bf(v.y); o[2]=f2bf(v.z); o[3]=f2bf(v.w);
    *(u16x4*)&xb[i] = o;
    return;
  }
  const int gr   = blockIdx.x*4 + (threadIdx.x>>6);  // output row 0..4095 (wave-uniform)
  const int lane = threadIdx.x & 63;
  const float* W; int row;
  if (gr < 1024)      { W = W0; row = gr; }
  else if (gr < 3072) { row = (gr-1024)>>1; W = (gr&1) ? W2 : W1; }
  else                { W = W3; row = gr-3072; }
  const float* wr = W + (size_t)row*DM;
  float4 v[4]; float s = 0.f;
  #pragma unroll
  for (int c=0;c<4;c++){
    v[c] = *(const float4*)&wr[c*256 + lane*4];
    s += fabsf(v[c].x)+fabsf(v[c].y)+fabsf(v[c].z)+fabsf(v[c].w);
  }
  #pragma unroll
  for (int off=32; off; off>>=1) s += __shfl_down(s, off);
  s = __shfl(s, 0);
  const float scale = fmaxf(s*(1.f/1024.f), 1e-5f);
  if (lane==0) wsc[gr] = scale;
  if (gr < 3072){
    u16* wo = wq + (size_t)gr*DM;
    #pragma unroll
    for (int c=0;c<4;c++){
      u16x4 q;
      q[0] = f2bf(fminf(fmaxf(rintf(v[c].x/scale),-1.f),1.f));
      q[1] = f2bf(fminf(fmaxf(rintf(v[c].y/scale),-1.f),1.f));
      q[2] = f2bf(fminf(fmaxf(rintf(v[c].z/scale),-1.f),1.f));
      q[3] = f2bf(fminf(fmaxf(rintf(v[c].w/scale),-1.f),1.f));
      *(u16x4*)&wo[c*256 + lane*4] = q;
    }
  } else {
    signed char* wo = wq8 + (size_t)(gr-3072)*DM;
    #pragma unroll
    for (int c=0;c<4;c++){
      const int q0 = (int)rintf(fminf(fmaxf(v[c].x/scale,-1.f),1.f));
      const int q1 = (int)rintf(fminf(fmaxf(v[c].y/scale,-1.f),1.f));
      const int q2 = (int)rintf(fminf(fmaxf(v[c].z/scale,-1.f),1.f));
      const int q3 = (int)rintf(fminf(fmaxf(v[c].w/scale,-1.f),1.f));
      const unsigned int p = (q0&0xFF) | ((q1&0xFF)<<8) | ((q2&0xFF)<<16) | ((unsigned)(q3&0xFF)<<24);
      *(unsigned int*)&wo[c*256 + lane*4] = p;
    }
  }
}

// ---------------- K2: m97-style 128x128 bf16 GEMM + fused chunk-sum epilogue --------
// N=3072; cols<1024 -> sigmoid -> r ; cols>=1024 interleaved k/v -> kv product AND
// per-chunk scaled sums -> part (plain stores, one producer per cell).
// Epilogue store order mi{r2{ni}}: the 4 ni-chunks of each 64B output line are issued
// back-to-back (full-line write combine, no RMW).  exp via reciprocal chains:
// 1/max(e,1e-10) == min(1/e,1e10); rc *= expf(-ldv) per row, *= expf(-16*ldv) per mi.
#define RD(base, off) (*(const bf16x8*)((const char*)(base) + (off)))

__global__ __launch_bounds__(256, 4)
void gemm_rkv(const u16* __restrict__ Ag, const u16* __restrict__ Bq,
              const float* __restrict__ bscale, const float* __restrict__ decay,
              u16* __restrict__ o_r, u16* __restrict__ o_kv,
              float* __restrict__ part)
{
  __shared__ u16 sA[128*64];
  __shared__ u16 sB[128*64];
  const int tid = threadIdx.x, wave = tid>>6, lane = tid&63;
  const int lr = lane&15, lg = lane>>4;
  const int wm = wave>>1, wn = wave&1;
  const int bm0 = blockIdx.x*128, bn0 = blockIdx.y*128;
  constexpr int nt = 16;

  const int r8   = lane>>3;
  const int scol = ((lane&7)<<4) ^ (r8<<4);
  const size_t aoff = (size_t)(bm0 + wave*8 + r8)*2048 + scol;
  const size_t boff = (size_t)(bn0 + wave*8 + r8)*2048 + scol;
  const int ldst = wave*1024;

  const int S = (lr&7)<<4;
  const int koff0 = ((lg<<4)     ) ^ S;
  const int koff1 = (64 + (lg<<4)) ^ S;
  const int arow = (wm*64 + lr)*128;
  const int brow = (wn*64 + lr)*128;

  f32x4 acc[4][4];
  #pragma unroll
  for (int i=0;i<4;i++)
    #pragma unroll
    for (int j=0;j<4;j++) acc[i][j] = (f32x4){0.f,0.f,0.f,0.f};

  for (int t=0; t<nt; ++t){
    #pragma unroll
    for (int q=0;q<4;q++){
      __builtin_amdgcn_global_load_lds(
        (const __attribute__((address_space(1))) void*)((const char*)Ag + aoff + q*65536 + (size_t)t*128),
        (__attribute__((address_space(3))) void*)((char*)sA + ldst + q*4096), 16, 0, 0);
      __builtin_amdgcn_global_load_lds(
        (const __attribute__((address_space(1))) void*)((const char*)Bq + boff + q*65536 + (size_t)t*128),
        (__attribute__((address_space(3))) void*)((char*)sB + ldst + q*4096), 16, 0, 0);
    }
    __syncthreads();
    {
      bf16x8 a[4], b[4];
      #pragma unroll
      for (int m=0;m<4;m++) a[m] = RD(sA, arow + m*2048 + koff0);
      #pragma unroll
      for (int n=0;n<4;n++) b[n] = RD(sB, brow + n*2048 + koff0);
      #pragma unroll
      for (int m=0;m<4;m++)
        #pragma unroll
        for (int n=0;n<4;n++)
          acc[m][n] = __builtin_amdgcn_mfma_f32_16x16x32_bf16(a[m], b[n], acc[m][n], 0,0,0);
      #pragma unroll
      for (int m=0;m<4;m++) a[m] = RD(sA, arow + m*2048 + koff1);
      #pragma unroll
      for (int n=0;n<4;n++) b[n] = RD(sB, brow + n*2048 + koff1);
      #pragma unroll
      for (int m=0;m<4;m++)
        #pragma unroll
        for (int n=0;n<4;n++)
          acc[m][n] = __builtin_amdgcn_mfma_f32_16x16x32_bf16(a[m], b[n], acc[m][n], 0,0,0);
    }
    __syncthreads();
  }

  // ---- epilogue: C/D col=lane&15, row=(lane>>4)*4+reg ----
  if (bn0 < 1024){                              // r segment (block-uniform)
    float sc[4];
    #pragma unroll
    for (int ni=0;ni<4;ni++) sc[ni] = bscale[bn0 + wn*64 + ni*16 + lr];
    #pragma unroll
    for (int mi=0; mi<4; ++mi){
      const int rowb = bm0 + wm*64 + mi*16 + lg*4;
      #pragma unroll
      for (int r2=0;r2<4;r2++){
        #pragma unroll
        for (int ni=0; ni<4; ++ni){                    // 4 ni = 128B contiguous
          const int col = bn0 + wn*64 + ni*16 + lr;
          const float val = acc[mi][ni][r2]*sc[ni];
          o_r[(size_t)(rowb+r2)*DM + col] = f2bf(1.f/(1.f+expf(-val)));
        }
      }
    }
  } else {                                      // interleaved k/v -> kv + chunk sums
    float sc[4], E1i[4], E16i[4], rcc[4];
    int dv[4];
    const int tb = (bm0 & 4095) + wm*64 + lg*4; // t of (mi=0, r2=0)
    #pragma unroll
    for (int ni=0; ni<4; ++ni){
      const int col = bn0 + wn*64 + ni*16 + lr;
      sc[ni] = bscale[col];
      dv[ni] = (col - 1024) >> 1;
      const float dec = 1.f/(1.f+expf(-decay[dv[ni]]));
      const float ldv = logf(fmaxf(dec, 1e-7f));
      E1i[ni]  = expf(-ldv);
      E16i[ni] = expf(-16.f*ldv);
      rcc[ni]  = expf(-(float)tb*ldv);          // 1/e at t=tb (inf ok -> clipped)
    }
    float s0[4] = {0.f,0.f,0.f,0.f}, s1[4] = {0.f,0.f,0.f,0.f};
    #pragma unroll
    for (int mi=0; mi<4; ++mi){
      const int rowb = bm0 + wm*64 + mi*16 + lg*4;
      float rc[4];
      #pragma unroll
      for (int ni=0;ni<4;ni++) rc[ni] = rcc[ni];
      #pragma unroll
      for (int r2=0;r2<4;r2++){
        #pragma unroll
        for (int ni=0; ni<4; ++ni){                    // 4 ni = one 64B kv line
          const float val = acc[mi][ni][r2]*sc[ni];
          const float pr  = val * __shfl_xor(val, 1);  // k*v (pair-symmetric)
          if (!(lr & 1))
            o_kv[(size_t)(rowb+r2)*DM + dv[ni]] = f2bf(pr);
          const float sv = pr * fminf(rc[ni], 1e10f);  // == pr/max(e,1e-10)
          if (mi < 2) s0[ni] += sv; else s1[ni] += sv;
          rc[ni] *= E1i[ni];
        }
      }
      #pragma unroll
      for (int ni=0;ni<4;ni++) rcc[ni] *= E16i[ni];
    }
    #pragma unroll
    for (int ni=0;ni<4;ni++){
      s0[ni] += __shfl_down(s0[ni], 32); s0[ni] += __shfl_down(s0[ni], 16);
      s1[ni] += __shfl_down(s1[ni], 32); s1[ni] += __shfl_down(s1[ni], 16);
    }
    if ((lane < 16) && !(lane & 1)){
      const int bb = bm0 >> 12;
      const int c0 = ((bm0 & 4095) + wm*64) >> 5;
      #pragma unroll
      for (int ni=0;ni<4;ni++)                         // grouped: 4x32B contiguous
        part[((size_t)(bb*128 + c0    ))*DM + dv[ni]] = s0[ni];
      #pragma unroll
      for (int ni=0;ni<4;ni++)
        part[((size_t)(bb*128 + c0 + 1))*DM + dv[ni]] = s1[ni];
    }
  }
}

// ---------------- K6: i8 GEMM for the Wo projection (2x MFMA rate, exact i32 acc) ----
#define RD8(base, off) (*(const i32x4*)((const char*)(base) + (off)))

__global__ __launch_bounds__(256, 4)
void gemm_o8(const signed char* __restrict__ Ag, const signed char* __restrict__ Bq,
             const float* __restrict__ bscale, const float* __restrict__ sxr,
             float* __restrict__ o_f)
{
  __shared__ signed char sA[128*128];           // 16KB
  __shared__ signed char sB[128*128];           // 16KB
  const int tid = threadIdx.x, wave = tid>>6, lane = tid&63;
  const int lr = lane&15, lg = lane>>4;
  const int wm = wave>>1, wn = wave&1;
  const int bm0 = blockIdx.x*128, bn0 = blockIdx.y*128;
  constexpr int nt = 8;                         // K = 1024 i8 / 128B

  const int r8   = lane>>3;
  const int scol = ((lane&7)<<4) ^ (r8<<4);
  const size_t aoff = (size_t)(bm0 + wave*8 + r8)*1024 + scol;
  const size_t boff = (size_t)(bn0 + wave*8 + r8)*1024 + scol;
  const int ldst = wave*1024;

  const int S = (lr&7)<<4;
  const int koff0 = ((lg<<4)     ) ^ S;
  const int koff1 = (64 + (lg<<4)) ^ S;
  const int arow = (wm*64 + lr)*128;
  const int brow = (wn*64 + lr)*128;

  i32x4 acc[4][4];
  #pragma unroll
  for (int i=0;i<4;i++)
    #pragma unroll
    for (int j=0;j<4;j++) acc[i][j] = (i32x4){0,0,0,0};

  for (int t=0; t<nt; ++t){
    #pragma unroll
    for (int q=0;q<4;q++){
      __builtin_amdgcn_global_load_lds(
        (const __attribute__((address_space(1))) void*)((const char*)Ag + aoff + q*32768 + (size_t)t*128),
        (__attribute__((address_space(3))) void*)((char*)sA + ldst + q*4096), 16, 0, 0);
      __builtin_amdgcn_global_load_lds(
        (const __attribute__((address_space(1))) void*)((const char*)Bq + boff + q*32768 + (size_t)t*128),
        (__attribute__((address_space(3))) void*)((char*)sB + ldst + q*4096), 16, 0, 0);
    }
    __syncthreads();
    {
      i32x4 a[4], b[4];
      #pragma unroll
      for (int m=0;m<4;m++) a[m] = RD8(sA, arow + m*2048 + koff0);
      #pragma unroll
      for (int n=0;n<4;n++) b[n] = RD8(sB, brow + n*2048 + koff0);
      #pragma unroll
      for (int m=0;m<4;m++)
        #pragma unroll
        for (int n=0;n<4;n++)
          acc[m][n] = __builtin_amdgcn_mfma_i32_16x16x64_i8(a[m], b[n], acc[m][n], 0,0,0);
      #pragma unroll
      for (int m=0;m<4;m++) a[m] = RD8(sA, arow + m*2048 + koff1);
      #pragma unroll
      for (int n=0;n<4;n++) b[n] = RD8(sB, brow + n*2048 + koff1);
      #pragma unroll
      for (int m=0;m<4;m++)
        #pragma unroll
        for (int n=0;n<4;n++)
          acc[m][n] = __builtin_amdgcn_mfma_i32_16x16x64_i8(a[m], b[n], acc[m][n], 0,0,0);
    }
    __syncthreads();
  }

  #pragma unroll
  for (int mi=0; mi<4; ++mi){
    const int rowb = bm0 + wm*64 + mi*16 + lg*4;
    float sx[4];
    #pragma unroll
    for (int r2=0;r2<4;r2++) sx[r2] = sxr[rowb+r2];
    #pragma unroll
    for (int r2=0;r2<4;r2++){
      #pragma unroll
      for (int ni=0; ni<4; ++ni){                      // 4 ni = 256B contiguous f32
        const int col = bn0 + wn*64 + ni*16 + lr;
        o_f[(size_t)(rowb+r2)*DM + col] = (float)acc[mi][ni][r2] * sx[r2] * bscale[col];
      }
    }
  }
}

// ---------------- K4: exclusive prefix over 128 chunk sums (16 blocks, 1 d/thread) --
__global__ void chunk_prefix(float* __restrict__ part){
  const int g = blockIdx.x*256 + threadIdx.x;  // 0..4095
  const int b = g >> 10, d = g & 1023;
  float run = 0.f;
  for (int c8=0; c8<128; c8+=8){
    float v[8];
    #pragma unroll
    for (int i=0;i<8;i++)
      v[i] = part[((size_t)(b*128+c8+i))*DM + d];
    #pragma unroll
    for (int i=0;i<8;i++){
      const float tmp = v[i];
      part[((size_t)(b*128+c8+i))*DM + d] = run;
      run += tmp;
    }
  }
}

// ---------------- K5: scan + y=r*state + rmsnorm -> i8 yn (per-row scale) -----------
__global__ __launch_bounds__(256)
void scan_norm(const u16* __restrict__ kv, const u16* __restrict__ rbuf,
               const float* __restrict__ part, const float* __restrict__ decay,
               const float* __restrict__ lnw, signed char* __restrict__ yn8,
               float* __restrict__ sxr)
{
  const int c = blockIdx.x & 127, b = blockIdx.x >> 7;
  const int tid = threadIdx.x, lane = tid&63, wave = tid>>6;
  const int d0 = tid*4;
  __shared__ float redS[2][4];
  __shared__ float redM[2][4];
  f32x4 run = *(const f32x4*)&part[((size_t)(b*128+c))*DM + d0];
  float ld[4], lw[4];
  #pragma unroll
  for (int j=0;j<4;j++){
    const float dec = 1.f/(1.f+expf(-decay[d0+j]));
    ld[j] = logf(fmaxf(dec, 1e-7f));
    lw[j] = lnw[d0+j];
  }
  for (int t=c*32; t<c*32+32; ++t){
    const size_t base = ((size_t)(b*4096+t))*DM + d0;
    const u16x4 p4 = *(const u16x4*)&kv[base];
    const u16x4 r4 = *(const u16x4*)&rbuf[base];
    const float tf = (float)t;
    float yl[4]; float ss = 0.f, mx = 0.f;
    #pragma unroll
    for (int j=0;j<4;j++){
      const float e = expf(tf*ld[j]);
      run[j] += bf2f(p4[j]) / fmaxf(e, 1e-10f);
      const float st = run[j]*e;                             // unclipped, underflows like ref
      const float y = bf2f(r4[j])*st;
      ss += y*y;
      yl[j] = y*lw[j];
      mx = fmaxf(mx, fabsf(yl[j]));
    }
    #pragma unroll
    for (int off=32; off; off>>=1){
      ss += __shfl_down(ss, off);
      mx  = fmaxf(mx, __shfl_down(mx, off));
    }
    if (lane==0){ redS[t&1][wave] = ss; redM[t&1][wave] = mx; }
    __builtin_amdgcn_s_barrier();
    const float tot = (redS[t&1][0]+redS[t&1][1])+(redS[t&1][2]+redS[t&1][3]);
    const float m1  = fmaxf(fmaxf(redM[t&1][0],redM[t&1][1]),
                            fmaxf(redM[t&1][2],redM[t&1][3]));
    const float rs  = 1.f/sqrtf(tot*(1.f/1024.f) + 1e-6f);
    const float m1s = fmaxf(m1, 1e-30f);
    const float qk  = 127.f/m1s;
    if (tid==0) sxr[b*4096+t] = m1s*rs*(1.f/127.f);
    unsigned int p = 0;
    #pragma unroll
    for (int j=0;j<4;j++){
      int q = (int)rintf(yl[j]*qk);
      q = q>127?127:(q<-127?-127:q);
      p |= ((unsigned)(q&0xFF)) << (8*j);
    }
    *(unsigned int*)&yn8[base] = p;
  }
}

extern "C" void kernel_launch(void* const* d_in, const int* in_sizes, int n_in,
                              void* d_out, int out_size, void* d_ws, size_t ws_size,
                              hipStream_t stream)
{
  (void)in_sizes; (void)n_in; (void)out_size; (void)ws_size;
  const float* x    = (const float*)d_in[0];
  const float* Wr   = (const float*)d_in[1];
  const float* Wk   = (const float*)d_in[2];
  const float* Wv   = (const float*)d_in[3];
  const float* Wo   = (const float*)d_in[4];
  const float* dec  = (const float*)d_in[5];
  const float* lnw  = (const float*)d_in[6];

  // layout: wq 6MB | wq8 1MB | wsc 16KB | rbuf 33.5MB | kvbuf 33.5MB | part 2MB |
  //         xb 33.5MB | yn8 16.8MB | sxr 64KB
  char* ws = (char*)d_ws;
  u16*         wq    = (u16*)(ws + 0);
  signed char* wq8   = (signed char*)(ws + 6291456);
  float*       wsc   = (float*)(ws + 7340032);
  u16*         rbuf  = (u16*)(ws + 7356416);
  u16*         kvbuf = (u16*)(ws + 40910848);
  float*       part  = (float*)(ws + 74465280);
  u16*         xb    = (u16*)(ws + 76562432);
  signed char* yn8   = (signed char*)(ws + 110116864);
  float*       sxr   = (float*)(ws + 126894080);   // ends 126,959,616

  init_pack<<<17408, 256, 0, stream>>>(Wr, Wk, Wv, Wo, x, wq, wq8, wsc, xb);
  gemm_rkv<<<dim3(128,24), 256, 0, stream>>>(xb, wq, wsc, dec, rbuf, kvbuf, part);
  chunk_prefix<<<16, 256, 0, stream>>>(part);
  scan_norm<<<512, 256, 0, stream>>>(kvbuf, rbuf, part, dec, lnw, yn8, sxr);
  gemm_o8<<<dim3(128,8), 256, 0, stream>>>(yn8, wq8, wsc + 3072, sxr, (float*)d_out);
}

// Round 12
// 228.612 us; speedup vs baseline: 1.0158x; 1.0158x over previous
//
#include <hip/hip_runtime.h>

typedef unsigned short u16;
typedef __attribute__((ext_vector_type(8))) short bf16x8;
typedef __attribute__((ext_vector_type(4))) float f32x4;
typedef __attribute__((ext_vector_type(4))) int   i32x4;
typedef __attribute__((ext_vector_type(4))) unsigned short u16x4;

#define DM 1024

__device__ __forceinline__ float bf2f(u16 u){
  union { unsigned int i; float f; } v; v.i = ((unsigned int)u)<<16; return v.f;
}
__device__ __forceinline__ u16 f2bf(float f){
  unsigned int x = __float_as_uint(f);
  return (u16)((x + 0x7FFFu + ((x>>16)&1u)) >> 16);   // RNE, finite inputs only
}

// ---------------- K0: fused weight-quantize (blocks 0..1023) + x->bf16 (rest) -------
// wq (bf16) rows: [0,1024) = R ; [1024,3072) = K[d],V[d] interleaved.
// wq8 (i8)  rows: [0,1024) = O (ternary exact in i8).  wsc: all 4096 rows.
__global__ __launch_bounds__(256)
void init_pack(const float* __restrict__ W0, const float* __restrict__ W1,
               const float* __restrict__ W2, const float* __restrict__ W3,
               const float* __restrict__ x,
               u16* __restrict__ wq, signed char* __restrict__ wq8,
               float* __restrict__ wsc, u16* __restrict__ xb)
{
  if (blockIdx.x >= 1024){                     // ---- x f32 -> bf16 ----
    const int i = ((blockIdx.x-1024)*256 + threadIdx.x)*4;
    float4 v = *(const float4*)&x[i];
    u16x4 o; o[0]=f2bf(v.x); o[1]=f2bf(v.y); o[2]=f2bf(v.z); o[3]=f2bf(v.w);
    *(u16x4*)&xb[i] = o;
    return;
  }
  const int gr   = blockIdx.x*4 + (threadIdx.x>>6);  // output row 0..4095 (wave-uniform)
  const int lane = threadIdx.x & 63;
  const float* W; int row;
  if (gr < 1024)      { W = W0; row = gr; }
  else if (gr < 3072) { row = (gr-1024)>>1; W = (gr&1) ? W2 : W1; }
  else                { W = W3; row = gr-3072; }
  const float* wr = W + (size_t)row*DM;
  float4 v[4]; float s = 0.f;
  #pragma unroll
  for (int c=0;c<4;c++){
    v[c] = *(const float4*)&wr[c*256 + lane*4];
    s += fabsf(v[c].x)+fabsf(v[c].y)+fabsf(v[c].z)+fabsf(v[c].w);
  }
  #pragma unroll
  for (int off=32; off; off>>=1) s += __shfl_down(s, off);
  s = __shfl(s, 0);
  const float scale = fmaxf(s*(1.f/1024.f), 1e-5f);
  if (lane==0) wsc[gr] = scale;
  if (gr < 3072){
    u16* wo = wq + (size_t)gr*DM;
    #pragma unroll
    for (int c=0;c<4;c++){
      u16x4 q;
      q[0] = f2bf(fminf(fmaxf(rintf(v[c].x/scale),-1.f),1.f));
      q[1] = f2bf(fminf(fmaxf(rintf(v[c].y/scale),-1.f),1.f));
      q[2] = f2bf(fminf(fmaxf(rintf(v[c].z/scale),-1.f),1.f));
      q[3] = f2bf(fminf(fmaxf(rintf(v[c].w/scale),-1.f),1.f));
      *(u16x4*)&wo[c*256 + lane*4] = q;
    }
  } else {
    signed char* wo = wq8 + (size_t)(gr-3072)*DM;
    #pragma unroll
    for (int c=0;c<4;c++){
      const int q0 = (int)rintf(fminf(fmaxf(v[c].x/scale,-1.f),1.f));
      const int q1 = (int)rintf(fminf(fmaxf(v[c].y/scale,-1.f),1.f));
      const int q2 = (int)rintf(fminf(fmaxf(v[c].z/scale,-1.f),1.f));
      const int q3 = (int)rintf(fminf(fmaxf(v[c].w/scale,-1.f),1.f));
      const unsigned int p = (q0&0xFF) | ((q1&0xFF)<<8) | ((q2&0xFF)<<16) | ((unsigned)(q3&0xFF)<<24);
      *(unsigned int*)&wo[c*256 + lane*4] = p;
    }
  }
}

// ---------------- K2: m97-style 128x128 bf16 GEMM + fused chunk-sum epilogue --------
// TWO-PASS epilogue: pass 1 = tight stores only (R9 temporal density -> L2 line
// combining, no RMW); pass 2 = re-walk acc for the per-chunk scaled sums (expf
// reciprocal chains), part stores.  Product re-rounded through bf16 in pass 2 so
// part sums match scan_norm's rounded-kv reads.
#define RD(base, off) (*(const bf16x8*)((const char*)(base) + (off)))

__global__ __launch_bounds__(256, 4)
void gemm_rkv(const u16* __restrict__ Ag, const u16* __restrict__ Bq,
              const float* __restrict__ bscale, const float* __restrict__ decay,
              u16* __restrict__ o_r, u16* __restrict__ o_kv,
              float* __restrict__ part)
{
  __shared__ u16 sA[128*64];
  __shared__ u16 sB[128*64];
  const int tid = threadIdx.x, wave = tid>>6, lane = tid&63;
  const int lr = lane&15, lg = lane>>4;
  const int wm = wave>>1, wn = wave&1;
  const int bm0 = blockIdx.x*128, bn0 = blockIdx.y*128;
  constexpr int nt = 16;

  const int r8   = lane>>3;
  const int scol = ((lane&7)<<4) ^ (r8<<4);
  const size_t aoff = (size_t)(bm0 + wave*8 + r8)*2048 + scol;
  const size_t boff = (size_t)(bn0 + wave*8 + r8)*2048 + scol;
  const int ldst = wave*1024;

  const int S = (lr&7)<<4;
  const int koff0 = ((lg<<4)     ) ^ S;
  const int koff1 = (64 + (lg<<4)) ^ S;
  const int arow = (wm*64 + lr)*128;
  const int brow = (wn*64 + lr)*128;

  f32x4 acc[4][4];
  #pragma unroll
  for (int i=0;i<4;i++)
    #pragma unroll
    for (int j=0;j<4;j++) acc[i][j] = (f32x4){0.f,0.f,0.f,0.f};

  for (int t=0; t<nt; ++t){
    #pragma unroll
    for (int q=0;q<4;q++){
      __builtin_amdgcn_global_load_lds(
        (const __attribute__((address_space(1))) void*)((const char*)Ag + aoff + q*65536 + (size_t)t*128),
        (__attribute__((address_space(3))) void*)((char*)sA + ldst + q*4096), 16, 0, 0);
      __builtin_amdgcn_global_load_lds(
        (const __attribute__((address_space(1))) void*)((const char*)Bq + boff + q*65536 + (size_t)t*128),
        (__attribute__((address_space(3))) void*)((char*)sB + ldst + q*4096), 16, 0, 0);
    }
    __syncthreads();
    {
      bf16x8 a[4], b[4];
      #pragma unroll
      for (int m=0;m<4;m++) a[m] = RD(sA, arow + m*2048 + koff0);
      #pragma unroll
      for (int n=0;n<4;n++) b[n] = RD(sB, brow + n*2048 + koff0);
      #pragma unroll
      for (int m=0;m<4;m++)
        #pragma unroll
        for (int n=0;n<4;n++)
          acc[m][n] = __builtin_amdgcn_mfma_f32_16x16x32_bf16(a[m], b[n], acc[m][n], 0,0,0);
      #pragma unroll
      for (int m=0;m<4;m++) a[m] = RD(sA, arow + m*2048 + koff1);
      #pragma unroll
      for (int n=0;n<4;n++) b[n] = RD(sB, brow + n*2048 + koff1);
      #pragma unroll
      for (int m=0;m<4;m++)
        #pragma unroll
        for (int n=0;n<4;n++)
          acc[m][n] = __builtin_amdgcn_mfma_f32_16x16x32_bf16(a[m], b[n], acc[m][n], 0,0,0);
    }
    __syncthreads();
  }

  // ---- epilogue: C/D col=lane&15, row=(lane>>4)*4+reg ----
  if (bn0 < 1024){                              // r segment (block-uniform)
    float sc[4];
    #pragma unroll
    for (int ni=0;ni<4;ni++) sc[ni] = bscale[bn0 + wn*64 + ni*16 + lr];
    #pragma unroll
    for (int mi=0; mi<4; ++mi){
      const int rowb = bm0 + wm*64 + mi*16 + lg*4;
      #pragma unroll
      for (int r2=0;r2<4;r2++){
        #pragma unroll
        for (int ni=0; ni<4; ++ni){                    // 4 ni = 128B contiguous
          const int col = bn0 + wn*64 + ni*16 + lr;
          const float val = acc[mi][ni][r2]*sc[ni];
          o_r[(size_t)(rowb+r2)*DM + col] = f2bf(1.f/(1.f+expf(-val)));
        }
      }
    }
  } else {                                      // interleaved k/v
    float sc[4]; int dv[4];
    #pragma unroll
    for (int ni=0; ni<4; ++ni){
      const int col = bn0 + wn*64 + ni*16 + lr;
      sc[ni] = bscale[col];
      dv[ni] = (col - 1024) >> 1;
    }
    // ---- pass 1: TIGHT kv stores (no transcendental work in between) ----
    #pragma unroll
    for (int mi=0; mi<4; ++mi){
      const int rowb = bm0 + wm*64 + mi*16 + lg*4;
      #pragma unroll
      for (int r2=0;r2<4;r2++){
        #pragma unroll
        for (int ni=0; ni<4; ++ni){                    // 4 ni = one 64B kv half-line
          const float val = acc[mi][ni][r2]*sc[ni];
          const float pr  = val * __shfl_xor(val, 1);  // k*v (pair-symmetric)
          if (!(lr & 1))
            o_kv[(size_t)(rowb+r2)*DM + dv[ni]] = f2bf(pr);
        }
      }
    }
    // ---- pass 2: per-chunk scaled sums (reciprocal chains; rounded product) ----
    float E1i[4], E16i[4], rcc[4];
    const int tb = (bm0 & 4095) + wm*64 + lg*4;        // t of (mi=0, r2=0)
    #pragma unroll
    for (int ni=0; ni<4; ++ni){
      const float dec = 1.f/(1.f+expf(-decay[dv[ni]]));
      const float ldv = logf(fmaxf(dec, 1e-7f));
      E1i[ni]  = expf(-ldv);
      E16i[ni] = expf(-16.f*ldv);
      rcc[ni]  = expf(-(float)tb*ldv);                 // 1/e at t=tb (inf ok -> clipped)
    }
    float s0[4] = {0.f,0.f,0.f,0.f}, s1[4] = {0.f,0.f,0.f,0.f};
    #pragma unroll
    for (int mi=0; mi<4; ++mi){
      float rc[4];
      #pragma unroll
      for (int ni=0;ni<4;ni++) rc[ni] = rcc[ni];
      #pragma unroll
      for (int r2=0;r2<4;r2++){
        #pragma unroll
        for (int ni=0; ni<4; ++ni){
          const float val = acc[mi][ni][r2]*sc[ni];
          const float pr  = bf2f(f2bf(val * __shfl_xor(val, 1)));  // rounded like kvbuf
          const float sv  = pr * fminf(rc[ni], 1e10f);             // == pr/max(e,1e-10)
          if (mi < 2) s0[ni] += sv; else s1[ni] += sv;
          rc[ni] *= E1i[ni];
        }
      }
      #pragma unroll
      for (int ni=0;ni<4;ni++) rcc[ni] *= E16i[ni];
    }
    #pragma unroll
    for (int ni=0;ni<4;ni++){
      s0[ni] += __shfl_down(s0[ni], 32); s0[ni] += __shfl_down(s0[ni], 16);
      s1[ni] += __shfl_down(s1[ni], 32); s1[ni] += __shfl_down(s1[ni], 16);
    }
    if ((lane < 16) && !(lane & 1)){
      const int bb = bm0 >> 12;
      const int c0 = ((bm0 & 4095) + wm*64) >> 5;
      #pragma unroll
      for (int ni=0;ni<4;ni++)
        part[((size_t)(bb*128 + c0    ))*DM + dv[ni]] = s0[ni];
      #pragma unroll
      for (int ni=0;ni<4;ni++)
        part[((size_t)(bb*128 + c0 + 1))*DM + dv[ni]] = s1[ni];
    }
  }
}

// ---------------- K6: i8 GEMM for the Wo projection (2x MFMA rate, exact i32 acc) ----
#define RD8(base, off) (*(const i32x4*)((const char*)(base) + (off)))

__global__ __launch_bounds__(256, 4)
void gemm_o8(const signed char* __restrict__ Ag, const signed char* __restrict__ Bq,
             const float* __restrict__ bscale, const float* __restrict__ sxr,
             float* __restrict__ o_f)
{
  __shared__ signed char sA[128*128];           // 16KB
  __shared__ signed char sB[128*128];           // 16KB
  const int tid = threadIdx.x, wave = tid>>6, lane = tid&63;
  const int lr = lane&15, lg = lane>>4;
  const int wm = wave>>1, wn = wave&1;
  const int bm0 = blockIdx.x*128, bn0 = blockIdx.y*128;
  constexpr int nt = 8;                         // K = 1024 i8 / 128B

  const int r8   = lane>>3;
  const int scol = ((lane&7)<<4) ^ (r8<<4);
  const size_t aoff = (size_t)(bm0 + wave*8 + r8)*1024 + scol;
  const size_t boff = (size_t)(bn0 + wave*8 + r8)*1024 + scol;
  const int ldst = wave*1024;

  const int S = (lr&7)<<4;
  const int koff0 = ((lg<<4)     ) ^ S;
  const int koff1 = (64 + (lg<<4)) ^ S;
  const int arow = (wm*64 + lr)*128;
  const int brow = (wn*64 + lr)*128;

  i32x4 acc[4][4];
  #pragma unroll
  for (int i=0;i<4;i++)
    #pragma unroll
    for (int j=0;j<4;j++) acc[i][j] = (i32x4){0,0,0,0};

  for (int t=0; t<nt; ++t){
    #pragma unroll
    for (int q=0;q<4;q++){
      __builtin_amdgcn_global_load_lds(
        (const __attribute__((address_space(1))) void*)((const char*)Ag + aoff + q*32768 + (size_t)t*128),
        (__attribute__((address_space(3))) void*)((char*)sA + ldst + q*4096), 16, 0, 0);
      __builtin_amdgcn_global_load_lds(
        (const __attribute__((address_space(1))) void*)((const char*)Bq + boff + q*32768 + (size_t)t*128),
        (__attribute__((address_space(3))) void*)((char*)sB + ldst + q*4096), 16, 0, 0);
    }
    __syncthreads();
    {
      i32x4 a[4], b[4];
      #pragma unroll
      for (int m=0;m<4;m++) a[m] = RD8(sA, arow + m*2048 + koff0);
      #pragma unroll
      for (int n=0;n<4;n++) b[n] = RD8(sB, brow + n*2048 + koff0);
      #pragma unroll
      for (int m=0;m<4;m++)
        #pragma unroll
        for (int n=0;n<4;n++)
          acc[m][n] = __builtin_amdgcn_mfma_i32_16x16x64_i8(a[m], b[n], acc[m][n], 0,0,0);
      #pragma unroll
      for (int m=0;m<4;m++) a[m] = RD8(sA, arow + m*2048 + koff1);
      #pragma unroll
      for (int n=0;n<4;n++) b[n] = RD8(sB, brow + n*2048 + koff1);
      #pragma unroll
      for (int m=0;m<4;m++)
        #pragma unroll
        for (int n=0;n<4;n++)
          acc[m][n] = __builtin_amdgcn_mfma_i32_16x16x64_i8(a[m], b[n], acc[m][n], 0,0,0);
    }
    __syncthreads();
  }

  #pragma unroll
  for (int mi=0; mi<4; ++mi){
    const int rowb = bm0 + wm*64 + mi*16 + lg*4;
    float sx[4];
    #pragma unroll
    for (int r2=0;r2<4;r2++) sx[r2] = sxr[rowb+r2];
    #pragma unroll
    for (int r2=0;r2<4;r2++){
      #pragma unroll
      for (int ni=0; ni<4; ++ni){                      // 4 ni = 256B contiguous f32
        const int col = bn0 + wn*64 + ni*16 + lr;
        o_f[(size_t)(rowb+r2)*DM + col] = (float)acc[mi][ni][r2] * sx[r2] * bscale[col];
      }
    }
  }
}

// ---------------- K4: exclusive prefix over 128 chunk sums (16 blocks, 1 d/thread) --
__global__ void chunk_prefix(float* __restrict__ part){
  const int g = blockIdx.x*256 + threadIdx.x;  // 0..4095
  const int b = g >> 10, d = g & 1023;
  float run = 0.f;
  for (int c8=0; c8<128; c8+=8){
    float v[8];
    #pragma unroll
    for (int i=0;i<8;i++)
      v[i] = part[((size_t)(b*128+c8+i))*DM + d];
    #pragma unroll
    for (int i=0;i<8;i++){
      const float tmp = v[i];
      part[((size_t)(b*128+c8+i))*DM + d] = run;
      run += tmp;
    }
  }
}

// ---------------- K5: scan + y=r*state + rmsnorm -> i8 yn (per-row scale) -----------
__global__ __launch_bounds__(256)
void scan_norm(const u16* __restrict__ kv, const u16* __restrict__ rbuf,
               const float* __restrict__ part, const float* __restrict__ decay,
               const float* __restrict__ lnw, signed char* __restrict__ yn8,
               float* __restrict__ sxr)
{
  const int c = blockIdx.x & 127, b = blockIdx.x >> 7;
  const int tid = threadIdx.x, lane = tid&63, wave = tid>>6;
  const int d0 = tid*4;
  __shared__ float redS[2][4];
  __shared__ float redM[2][4];
  f32x4 run = *(const f32x4*)&part[((size_t)(b*128+c))*DM + d0];
  float ld[4], lw[4];
  #pragma unroll
  for (int j=0;j<4;j++){
    const float dec = 1.f/(1.f+expf(-decay[d0+j]));
    ld[j] = logf(fmaxf(dec, 1e-7f));
    lw[j] = lnw[d0+j];
  }
  for (int t=c*32; t<c*32+32; ++t){
    const size_t base = ((size_t)(b*4096+t))*DM + d0;
    const u16x4 p4 = *(const u16x4*)&kv[base];
    const u16x4 r4 = *(const u16x4*)&rbuf[base];
    const float tf = (float)t;
    float yl[4]; float ss = 0.f, mx = 0.f;
    #pragma unroll
    for (int j=0;j<4;j++){
      const float e = expf(tf*ld[j]);
      run[j] += bf2f(p4[j]) / fmaxf(e, 1e-10f);
      const float st = run[j]*e;                             // unclipped, underflows like ref
      const float y = bf2f(r4[j])*st;
      ss += y*y;
      yl[j] = y*lw[j];
      mx = fmaxf(mx, fabsf(yl[j]));
    }
    #pragma unroll
    for (int off=32; off; off>>=1){
      ss += __shfl_down(ss, off);
      mx  = fmaxf(mx, __shfl_down(mx, off));
    }
    if (lane==0){ redS[t&1][wave] = ss; redM[t&1][wave] = mx; }
    __builtin_amdgcn_s_barrier();
    const float tot = (redS[t&1][0]+redS[t&1][1])+(redS[t&1][2]+redS[t&1][3]);
    const float m1  = fmaxf(fmaxf(redM[t&1][0],redM[t&1][1]),
                            fmaxf(redM[t&1][2],redM[t&1][3]));
    const float rs  = 1.f/sqrtf(tot*(1.f/1024.f) + 1e-6f);
    const float m1s = fmaxf(m1, 1e-30f);
    const float qk  = 127.f/m1s;
    if (tid==0) sxr[b*4096+t] = m1s*rs*(1.f/127.f);
    unsigned int p = 0;
    #pragma unroll
    for (int j=0;j<4;j++){
      int q = (int)rintf(yl[j]*qk);
      q = q>127?127:(q<-127?-127:q);
      p |= ((unsigned)(q&0xFF)) << (8*j);
    }
    *(unsigned int*)&yn8[base] = p;
  }
}

extern "C" void kernel_launch(void* const* d_in, const int* in_sizes, int n_in,
                              void* d_out, int out_size, void* d_ws, size_t ws_size,
                              hipStream_t stream)
{
  (void)in_sizes; (void)n_in; (void)out_size; (void)ws_size;
  const float* x    = (const float*)d_in[0];
  const float* Wr   = (const float*)d_in[1];
  const float* Wk   = (const float*)d_in[2];
  const float* Wv   = (const float*)d_in[3];
  const float* Wo   = (const float*)d_in[4];
  const float* dec  = (const float*)d_in[5];
  const float* lnw  = (const float*)d_in[6];

  // layout: wq 6MB | wq8 1MB | wsc 16KB | rbuf 33.5MB | kvbuf 33.5MB | part 2MB |
  //         xb 33.5MB | yn8 16.8MB | sxr 64KB
  char* ws = (char*)d_ws;
  u16*         wq    = (u16*)(ws + 0);
  signed char* wq8   = (signed char*)(ws + 6291456);
  float*       wsc   = (float*)(ws + 7340032);
  u16*         rbuf  = (u16*)(ws + 7356416);
  u16*         kvbuf = (u16*)(ws + 40910848);
  float*       part  = (float*)(ws + 74465280);
  u16*         xb    = (u16*)(ws + 76562432);
  signed char* yn8   = (signed char*)(ws + 110116864);
  float*       sxr   = (float*)(ws + 126894080);   // ends 126,959,616

  init_pack<<<17408, 256, 0, stream>>>(Wr, Wk, Wv, Wo, x, wq, wq8, wsc, xb);
  gemm_rkv<<<dim3(128,24), 256, 0, stream>>>(xb, wq, wsc, dec, rbuf, kvbuf, part);
  chunk_prefix<<<16, 256, 0, stream>>>(part);
  scan_norm<<<512, 256, 0, stream>>>(kvbuf, rbuf, part, dec, lnw, yn8, sxr);
  gemm_o8<<<dim3(128,8), 256, 0, stream>>>(yn8, wq8, wsc + 3072, sxr, (float*)d_out);
}

// Round 13
// 225.819 us; speedup vs baseline: 1.0283x; 1.0124x over previous
//
#include <hip/hip_runtime.h>

typedef unsigned short u16;
typedef __attribute__((ext_vector_type(8))) short bf16x8;
typedef __attribute__((ext_vector_type(4))) float f32x4;
typedef __attribute__((ext_vector_type(4))) int   i32x4;
typedef __attribute__((ext_vector_type(4))) unsigned short u16x4;

#define DM 1024

__device__ __forceinline__ float bf2f(u16 u){
  union { unsigned int i; float f; } v; v.i = ((unsigned int)u)<<16; return v.f;
}
__device__ __forceinline__ u16 f2bf(float f){
  unsigned int x = __float_as_uint(f);
  return (u16)((x + 0x7FFFu + ((x>>16)&1u)) >> 16);   // RNE, finite inputs only
}

// ---------------- K0: ternary-quantize ----------------
// wq (bf16) rows: [0,1024) = R ; [1024,3072) = K[d],V[d] interleaved.
// wq8 (i8)  rows: [0,1024) = O (ternary exact in i8).  wsc: all 4096 rows.
__global__ __launch_bounds__(256)
void quantize_w(const float* __restrict__ W0, const float* __restrict__ W1,
                const float* __restrict__ W2, const float* __restrict__ W3,
                u16* __restrict__ wq, signed char* __restrict__ wq8,
                float* __restrict__ wsc)
{
  const int gr   = blockIdx.x*4 + (threadIdx.x>>6);  // output row 0..4095 (wave-uniform)
  const int lane = threadIdx.x & 63;
  const float* W; int row;
  if (gr < 1024)      { W = W0; row = gr; }
  else if (gr < 3072) { row = (gr-1024)>>1; W = (gr&1) ? W2 : W1; }
  else                { W = W3; row = gr-3072; }
  const float* wr = W + (size_t)row*DM;
  float4 v[4]; float s = 0.f;
  #pragma unroll
  for (int c=0;c<4;c++){
    v[c] = *(const float4*)&wr[c*256 + lane*4];
    s += fabsf(v[c].x)+fabsf(v[c].y)+fabsf(v[c].z)+fabsf(v[c].w);
  }
  #pragma unroll
  for (int off=32; off; off>>=1) s += __shfl_down(s, off);
  s = __shfl(s, 0);
  const float scale = fmaxf(s*(1.f/1024.f), 1e-5f);
  if (lane==0) wsc[gr] = scale;
  if (gr < 3072){
    u16* wo = wq + (size_t)gr*DM;
    #pragma unroll
    for (int c=0;c<4;c++){
      u16x4 q;
      q[0] = f2bf(fminf(fmaxf(rintf(v[c].x/scale),-1.f),1.f));
      q[1] = f2bf(fminf(fmaxf(rintf(v[c].y/scale),-1.f),1.f));
      q[2] = f2bf(fminf(fmaxf(rintf(v[c].z/scale),-1.f),1.f));
      q[3] = f2bf(fminf(fmaxf(rintf(v[c].w/scale),-1.f),1.f));
      *(u16x4*)&wo[c*256 + lane*4] = q;
    }
  } else {
    signed char* wo = wq8 + (size_t)(gr-3072)*DM;
    #pragma unroll
    for (int c=0;c<4;c++){
      const int q0 = (int)rintf(fminf(fmaxf(v[c].x/scale,-1.f),1.f));
      const int q1 = (int)rintf(fminf(fmaxf(v[c].y/scale,-1.f),1.f));
      const int q2 = (int)rintf(fminf(fmaxf(v[c].z/scale,-1.f),1.f));
      const int q3 = (int)rintf(fminf(fmaxf(v[c].w/scale,-1.f),1.f));
      const unsigned int p = (q0&0xFF) | ((q1&0xFF)<<8) | ((q2&0xFF)<<16) | ((unsigned)(q3&0xFF)<<24);
      *(unsigned int*)&wo[c*256 + lane*4] = p;
    }
  }
}

// ---------------- K1: x f32 -> bf16 ----------------
__global__ void cvt_x(const float* __restrict__ x, u16* __restrict__ xb){
  const int i = (blockIdx.x*256 + threadIdx.x)*4;
  float4 v = *(const float4*)&x[i];
  u16x4 o; o[0]=f2bf(v.x); o[1]=f2bf(v.y); o[2]=f2bf(v.z); o[3]=f2bf(v.w);
  *(u16x4*)&xb[i] = o;
}

// ---------------- K2: m97-style 128x128 single-buffer bf16 GEMM (912 TF, R8/R9) -----
// N=3072; cols<1024 -> sigmoid -> r ; cols>=1024 interleaved k/v -> kv product.
#define RD(base, off) (*(const bf16x8*)((const char*)(base) + (off)))

__global__ __launch_bounds__(256, 4)
void gemm_rkv(const u16* __restrict__ Ag, const u16* __restrict__ Bq,
              const float* __restrict__ bscale,
              u16* __restrict__ o_r, u16* __restrict__ o_kv)
{
  __shared__ u16 sA[128*64];
  __shared__ u16 sB[128*64];
  const int tid = threadIdx.x, wave = tid>>6, lane = tid&63;
  const int lr = lane&15, lg = lane>>4;
  const int wm = wave>>1, wn = wave&1;
  const int bm0 = blockIdx.x*128, bn0 = blockIdx.y*128;
  constexpr int nt = 16;

  const int r8   = lane>>3;
  const int scol = ((lane&7)<<4) ^ (r8<<4);
  const size_t aoff = (size_t)(bm0 + wave*8 + r8)*2048 + scol;
  const size_t boff = (size_t)(bn0 + wave*8 + r8)*2048 + scol;
  const int ldst = wave*1024;

  const int S = (lr&7)<<4;
  const int koff0 = ((lg<<4)     ) ^ S;
  const int koff1 = (64 + (lg<<4)) ^ S;
  const int arow = (wm*64 + lr)*128;
  const int brow = (wn*64 + lr)*128;

  f32x4 acc[4][4];
  #pragma unroll
  for (int i=0;i<4;i++)
    #pragma unroll
    for (int j=0;j<4;j++) acc[i][j] = (f32x4){0.f,0.f,0.f,0.f};

  for (int t=0; t<nt; ++t){
    #pragma unroll
    for (int q=0;q<4;q++){
      __builtin_amdgcn_global_load_lds(
        (const __attribute__((address_space(1))) void*)((const char*)Ag + aoff + q*65536 + (size_t)t*128),
        (__attribute__((address_space(3))) void*)((char*)sA + ldst + q*4096), 16, 0, 0);
      __builtin_amdgcn_global_load_lds(
        (const __attribute__((address_space(1))) void*)((const char*)Bq + boff + q*65536 + (size_t)t*128),
        (__attribute__((address_space(3))) void*)((char*)sB + ldst + q*4096), 16, 0, 0);
    }
    __syncthreads();
    {
      bf16x8 a[4], b[4];
      #pragma unroll
      for (int m=0;m<4;m++) a[m] = RD(sA, arow + m*2048 + koff0);
      #pragma unroll
      for (int n=0;n<4;n++) b[n] = RD(sB, brow + n*2048 + koff0);
      #pragma unroll
      for (int m=0;m<4;m++)
        #pragma unroll
        for (int n=0;n<4;n++)
          acc[m][n] = __builtin_amdgcn_mfma_f32_16x16x32_bf16(a[m], b[n], acc[m][n], 0,0,0);
      #pragma unroll
      for (int m=0;m<4;m++) a[m] = RD(sA, arow + m*2048 + koff1);
      #pragma unroll
      for (int n=0;n<4;n++) b[n] = RD(sB, brow + n*2048 + koff1);
      #pragma unroll
      for (int m=0;m<4;m++)
        #pragma unroll
        for (int n=0;n<4;n++)
          acc[m][n] = __builtin_amdgcn_mfma_f32_16x16x32_bf16(a[m], b[n], acc[m][n], 0,0,0);
    }
    __syncthreads();
  }

  #pragma unroll
  for (int mi=0; mi<4; ++mi){
    #pragma unroll
    for (int ni=0; ni<4; ++ni){
      const int col = bn0 + wn*64 + ni*16 + lr;
      const float sc = bscale[col];
      const int rowb = bm0 + wm*64 + mi*16 + lg*4;
      const f32x4 a = acc[mi][ni];
      if (bn0 < 1024){
        #pragma unroll
        for (int r2=0;r2<4;r2++){
          const float val = a[r2]*sc;
          o_r[(size_t)(rowb+r2)*DM + col] = f2bf(1.f/(1.f+expf(-val)));
        }
      } else {
        const int dv = (col - 1024) >> 1;
        #pragma unroll
        for (int r2=0;r2<4;r2++){
          const float val = a[r2]*sc;
          const float pr  = val * __shfl_xor(val, 1);
          if (!(lr & 1))
            o_kv[(size_t)(rowb+r2)*DM + dv] = f2bf(pr);
        }
      }
    }
  }
}

// ---------------- K6: i8 GEMM for the Wo projection (2x MFMA rate, exact i32 acc) ----
#define RD8(base, off) (*(const i32x4*)((const char*)(base) + (off)))

__global__ __launch_bounds__(256, 4)
void gemm_o8(const signed char* __restrict__ Ag, const signed char* __restrict__ Bq,
             const float* __restrict__ bscale, const float* __restrict__ sxr,
             float* __restrict__ o_f)
{
  __shared__ signed char sA[128*128];           // 16KB
  __shared__ signed char sB[128*128];           // 16KB
  const int tid = threadIdx.x, wave = tid>>6, lane = tid&63;
  const int lr = lane&15, lg = lane>>4;
  const int wm = wave>>1, wn = wave&1;
  const int bm0 = blockIdx.x*128, bn0 = blockIdx.y*128;
  constexpr int nt = 8;                         // K = 1024 i8 / 128B

  const int r8   = lane>>3;
  const int scol = ((lane&7)<<4) ^ (r8<<4);
  const size_t aoff = (size_t)(bm0 + wave*8 + r8)*1024 + scol;
  const size_t boff = (size_t)(bn0 + wave*8 + r8)*1024 + scol;
  const int ldst = wave*1024;

  const int S = (lr&7)<<4;
  const int koff0 = ((lg<<4)     ) ^ S;
  const int koff1 = (64 + (lg<<4)) ^ S;
  const int arow = (wm*64 + lr)*128;
  const int brow = (wn*64 + lr)*128;

  i32x4 acc[4][4];
  #pragma unroll
  for (int i=0;i<4;i++)
    #pragma unroll
    for (int j=0;j<4;j++) acc[i][j] = (i32x4){0,0,0,0};

  for (int t=0; t<nt; ++t){
    #pragma unroll
    for (int q=0;q<4;q++){
      __builtin_amdgcn_global_load_lds(
        (const __attribute__((address_space(1))) void*)((const char*)Ag + aoff + q*32768 + (size_t)t*128),
        (__attribute__((address_space(3))) void*)((char*)sA + ldst + q*4096), 16, 0, 0);
      __builtin_amdgcn_global_load_lds(
        (const __attribute__((address_space(1))) void*)((const char*)Bq + boff + q*32768 + (size_t)t*128),
        (__attribute__((address_space(3))) void*)((char*)sB + ldst + q*4096), 16, 0, 0);
    }
    __syncthreads();
    {
      i32x4 a[4], b[4];
      #pragma unroll
      for (int m=0;m<4;m++) a[m] = RD8(sA, arow + m*2048 + koff0);
      #pragma unroll
      for (int n=0;n<4;n++) b[n] = RD8(sB, brow + n*2048 + koff0);
      #pragma unroll
      for (int m=0;m<4;m++)
        #pragma unroll
        for (int n=0;n<4;n++)
          acc[m][n] = __builtin_amdgcn_mfma_i32_16x16x64_i8(a[m], b[n], acc[m][n], 0,0,0);
      #pragma unroll
      for (int m=0;m<4;m++) a[m] = RD8(sA, arow + m*2048 + koff1);
      #pragma unroll
      for (int n=0;n<4;n++) b[n] = RD8(sB, brow + n*2048 + koff1);
      #pragma unroll
      for (int m=0;m<4;m++)
        #pragma unroll
        for (int n=0;n<4;n++)
          acc[m][n] = __builtin_amdgcn_mfma_i32_16x16x64_i8(a[m], b[n], acc[m][n], 0,0,0);
    }
    __syncthreads();
  }

  #pragma unroll
  for (int mi=0; mi<4; ++mi){
    const int rowb = bm0 + wm*64 + mi*16 + lg*4;
    float sx[4];
    #pragma unroll
    for (int r2=0;r2<4;r2++) sx[r2] = sxr[rowb+r2];
    #pragma unroll
    for (int ni=0; ni<4; ++ni){
      const int col = bn0 + wn*64 + ni*16 + lr;
      const float sc = bscale[col];
      const i32x4 a = acc[mi][ni];
      #pragma unroll
      for (int r2=0;r2<4;r2++)
        o_f[(size_t)(rowb+r2)*DM + col] = (float)a[r2] * sx[r2] * sc;
    }
  }
}

// ---------------- K3: per-chunk RAW sums of kv / max(exp(t*ld),1e-10), CH=32 --------
__global__ __launch_bounds__(256)
void kv_phase1(const u16* __restrict__ kv, const float* __restrict__ decay,
               float* __restrict__ part)
{
  const int c = blockIdx.x & 127, b = blockIdx.x >> 7;
  const int d0 = threadIdx.x*4;
  float ld[4]; f32x4 sum = {0.f,0.f,0.f,0.f};
  #pragma unroll
  for (int j=0;j<4;j++){
    const float dec = 1.f/(1.f+expf(-decay[d0+j]));
    ld[j] = logf(fmaxf(dec, 1e-7f));
  }
  for (int t=c*32; t<c*32+32; ++t){
    const size_t base = ((size_t)(b*4096 + t))*DM + d0;
    const u16x4 p4 = *(const u16x4*)&kv[base];
    const float tf = (float)t;
    #pragma unroll
    for (int j=0;j<4;j++){
      const float e = expf(tf*ld[j]);                        // underflows to 0 like ref
      sum[j] += bf2f(p4[j]) / fmaxf(e, 1e-10f);
    }
  }
  *(f32x4*)&part[((size_t)(b*128+c))*DM + d0] = sum;
}

// ---------------- K5: self-prefix + scan + y=r*state + rmsnorm -> i8 yn -------------
// Exclusive prefix computed in-block from RAW part rows 0..c-1, summed in the SAME
// sequential order the old chunk_prefix kernel used -> bit-identical run value.
// part is 2MB (L2/L3-resident) so the extra reads are cheap.
__global__ __launch_bounds__(256)
void scan_norm(const u16* __restrict__ kv, const u16* __restrict__ rbuf,
               const float* __restrict__ part, const float* __restrict__ decay,
               const float* __restrict__ lnw, signed char* __restrict__ yn8,
               float* __restrict__ sxr)
{
  const int c = blockIdx.x & 127, b = blockIdx.x >> 7;
  const int tid = threadIdx.x, lane = tid&63, wave = tid>>6;
  const int d0 = tid*4;
  __shared__ float redS[2][4];
  __shared__ float redM[2][4];
  // ---- exclusive prefix over chunks 0..c-1 (sequential adds, 8-wide batched loads) --
  f32x4 run = {0.f,0.f,0.f,0.f};
  {
    int i = 0;
    for (; i+8 <= c; i += 8){
      f32x4 v[8];
      #pragma unroll
      for (int u=0;u<8;u++)
        v[u] = *(const f32x4*)&part[((size_t)(b*128+i+u))*DM + d0];
      #pragma unroll
      for (int u=0;u<8;u++) run += v[u];                    // ascending order (bit-exact)
    }
    for (; i < c; ++i)
      run += *(const f32x4*)&part[((size_t)(b*128+i))*DM + d0];
  }
  float ld[4], lw[4];
  #pragma unroll
  for (int j=0;j<4;j++){
    const float dec = 1.f/(1.f+expf(-decay[d0+j]));
    ld[j] = logf(fmaxf(dec, 1e-7f));
    lw[j] = lnw[d0+j];
  }
  for (int t=c*32; t<c*32+32; ++t){
    const size_t base = ((size_t)(b*4096+t))*DM + d0;
    const u16x4 p4 = *(const u16x4*)&kv[base];
    const u16x4 r4 = *(const u16x4*)&rbuf[base];
    const float tf = (float)t;
    float yl[4]; float ss = 0.f, mx = 0.f;
    #pragma unroll
    for (int j=0;j<4;j++){
      const float e = expf(tf*ld[j]);                        // same expr as kv_phase1
      run[j] += bf2f(p4[j]) / fmaxf(e, 1e-10f);
      const float st = run[j]*e;                             // unclipped, underflows like ref
      const float y = bf2f(r4[j])*st;
      ss += y*y;
      yl[j] = y*lw[j];
      mx = fmaxf(mx, fabsf(yl[j]));
    }
    #pragma unroll
    for (int off=32; off; off>>=1){
      ss += __shfl_down(ss, off);
      mx  = fmaxf(mx, __shfl_down(mx, off));
    }
    if (lane==0){ redS[t&1][wave] = ss; redM[t&1][wave] = mx; }
    __builtin_amdgcn_s_barrier();
    const float tot = (redS[t&1][0]+redS[t&1][1])+(redS[t&1][2]+redS[t&1][3]);
    const float m1  = fmaxf(fmaxf(redM[t&1][0],redM[t&1][1]),
                            fmaxf(redM[t&1][2],redM[t&1][3]));
    const float rs  = 1.f/sqrtf(tot*(1.f/1024.f) + 1e-6f);
    const float m1s = fmaxf(m1, 1e-30f);
    const float qk  = 127.f/m1s;
    if (tid==0) sxr[b*4096+t] = m1s*rs*(1.f/127.f);
    unsigned int p = 0;
    #pragma unroll
    for (int j=0;j<4;j++){
      int q = (int)rintf(yl[j]*qk);
      q = q>127?127:(q<-127?-127:q);
      p |= ((unsigned)(q&0xFF)) << (8*j);
    }
    *(unsigned int*)&yn8[base] = p;
  }
}

extern "C" void kernel_launch(void* const* d_in, const int* in_sizes, int n_in,
                              void* d_out, int out_size, void* d_ws, size_t ws_size,
                              hipStream_t stream)
{
  (void)in_sizes; (void)n_in; (void)out_size; (void)ws_size;
  const float* x    = (const float*)d_in[0];
  const float* Wr   = (const float*)d_in[1];
  const float* Wk   = (const float*)d_in[2];
  const float* Wv   = (const float*)d_in[3];
  const float* Wo   = (const float*)d_in[4];
  const float* dec  = (const float*)d_in[5];
  const float* lnw  = (const float*)d_in[6];

  // layout: wq 6MB | wq8 1MB | wsc 16KB | rbuf 33.5MB | kvbuf 33.5MB | part 2MB |
  //         xb 33.5MB | yn8 16.8MB | sxr 64KB
  char* ws = (char*)d_ws;
  u16*         wq    = (u16*)(ws + 0);
  signed char* wq8   = (signed char*)(ws + 6291456);
  float*       wsc   = (float*)(ws + 7340032);
  u16*         rbuf  = (u16*)(ws + 7356416);
  u16*         kvbuf = (u16*)(ws + 40910848);
  float*       part  = (float*)(ws + 74465280);
  u16*         xb    = (u16*)(ws + 76562432);
  signed char* yn8   = (signed char*)(ws + 110116864);
  float*       sxr   = (float*)(ws + 126894080);   // ends 126,959,616

  quantize_w<<<1024, 256, 0, stream>>>(Wr, Wk, Wv, Wo, wq, wq8, wsc);
  cvt_x<<<16384, 256, 0, stream>>>(x, xb);
  gemm_rkv<<<dim3(128,24), 256, 0, stream>>>(xb, wq, wsc, rbuf, kvbuf);
  kv_phase1<<<512, 256, 0, stream>>>(kvbuf, dec, part);
  scan_norm<<<512, 256, 0, stream>>>(kvbuf, rbuf, part, dec, lnw, yn8, sxr);
  gemm_o8<<<dim3(128,8), 256, 0, stream>>>(yn8, wq8, wsc + 3072, sxr, (float*)d_out);
}

// Round 14
// 202.520 us; speedup vs baseline: 1.1466x; 1.1150x over previous
//
#include <hip/hip_runtime.h>

typedef unsigned short u16;
typedef __attribute__((ext_vector_type(8))) short bf16x8;
typedef __attribute__((ext_vector_type(4))) float f32x4;
typedef __attribute__((ext_vector_type(4))) int   i32x4;
typedef __attribute__((ext_vector_type(4))) unsigned short u16x4;

#define DM 1024

__device__ __forceinline__ float bf2f(u16 u){
  union { unsigned int i; float f; } v; v.i = ((unsigned int)u)<<16; return v.f;
}
__device__ __forceinline__ u16 f2bf(float f){
  unsigned int x = __float_as_uint(f);
  return (u16)((x + 0x7FFFu + ((x>>16)&1u)) >> 16);   // RNE, finite inputs only
}

// ---------------- K0: fused weight-quantize (blocks 0..1023) + x->bf16 (rest) -------
// wq (bf16) rows: [0,1024) = R ; [1024,3072) = K[d],V[d] interleaved.
// wq8 (i8)  rows: [0,1024) = O (ternary exact in i8).  wsc: all 4096 rows.
__global__ __launch_bounds__(256)
void init_pack(const float* __restrict__ W0, const float* __restrict__ W1,
               const float* __restrict__ W2, const float* __restrict__ W3,
               const float* __restrict__ x,
               u16* __restrict__ wq, signed char* __restrict__ wq8,
               float* __restrict__ wsc, u16* __restrict__ xb)
{
  if (blockIdx.x >= 1024){                     // ---- x f32 -> bf16 ----
    const int i = ((blockIdx.x-1024)*256 + threadIdx.x)*4;
    float4 v = *(const float4*)&x[i];
    u16x4 o; o[0]=f2bf(v.x); o[1]=f2bf(v.y); o[2]=f2bf(v.z); o[3]=f2bf(v.w);
    *(u16x4*)&xb[i] = o;
    return;
  }
  const int gr   = blockIdx.x*4 + (threadIdx.x>>6);  // output row 0..4095 (wave-uniform)
  const int lane = threadIdx.x & 63;
  const float* W; int row;
  if (gr < 1024)      { W = W0; row = gr; }
  else if (gr < 3072) { row = (gr-1024)>>1; W = (gr&1) ? W2 : W1; }
  else                { W = W3; row = gr-3072; }
  const float* wr = W + (size_t)row*DM;
  float4 v[4]; float s = 0.f;
  #pragma unroll
  for (int c=0;c<4;c++){
    v[c] = *(const float4*)&wr[c*256 + lane*4];
    s += fabsf(v[c].x)+fabsf(v[c].y)+fabsf(v[c].z)+fabsf(v[c].w);
  }
  #pragma unroll
  for (int off=32; off; off>>=1) s += __shfl_down(s, off);
  s = __shfl(s, 0);
  const float scale = fmaxf(s*(1.f/1024.f), 1e-5f);
  if (lane==0) wsc[gr] = scale;
  if (gr < 3072){
    u16* wo = wq + (size_t)gr*DM;
    #pragma unroll
    for (int c=0;c<4;c++){
      u16x4 q;
      q[0] = f2bf(fminf(fmaxf(rintf(v[c].x/scale),-1.f),1.f));
      q[1] = f2bf(fminf(fmaxf(rintf(v[c].y/scale),-1.f),1.f));
      q[2] = f2bf(fminf(fmaxf(rintf(v[c].z/scale),-1.f),1.f));
      q[3] = f2bf(fminf(fmaxf(rintf(v[c].w/scale),-1.f),1.f));
      *(u16x4*)&wo[c*256 + lane*4] = q;
    }
  } else {
    signed char* wo = wq8 + (size_t)(gr-3072)*DM;
    #pragma unroll
    for (int c=0;c<4;c++){
      const int q0 = (int)rintf(fminf(fmaxf(v[c].x/scale,-1.f),1.f));
      const int q1 = (int)rintf(fminf(fmaxf(v[c].y/scale,-1.f),1.f));
      const int q2 = (int)rintf(fminf(fmaxf(v[c].z/scale,-1.f),1.f));
      const int q3 = (int)rintf(fminf(fmaxf(v[c].w/scale,-1.f),1.f));
      const unsigned int p = (q0&0xFF) | ((q1&0xFF)<<8) | ((q2&0xFF)<<16) | ((unsigned)(q3&0xFF)<<24);
      *(unsigned int*)&wo[c*256 + lane*4] = p;
    }
  }
}

// ---------------- K2: m97-style 128x128 single-buffer bf16 GEMM (912 TF, R8/R9) -----
// N=3072; cols<1024 -> sigmoid -> r ; cols>=1024 interleaved k/v -> kv product.
#define RD(base, off) (*(const bf16x8*)((const char*)(base) + (off)))

__global__ __launch_bounds__(256, 4)
void gemm_rkv(const u16* __restrict__ Ag, const u16* __restrict__ Bq,
              const float* __restrict__ bscale,
              u16* __restrict__ o_r, u16* __restrict__ o_kv)
{
  __shared__ u16 sA[128*64];
  __shared__ u16 sB[128*64];
  const int tid = threadIdx.x, wave = tid>>6, lane = tid&63;
  const int lr = lane&15, lg = lane>>4;
  const int wm = wave>>1, wn = wave&1;
  const int bm0 = blockIdx.x*128, bn0 = blockIdx.y*128;
  constexpr int nt = 16;

  const int r8   = lane>>3;
  const int scol = ((lane&7)<<4) ^ (r8<<4);
  const size_t aoff = (size_t)(bm0 + wave*8 + r8)*2048 + scol;
  const size_t boff = (size_t)(bn0 + wave*8 + r8)*2048 + scol;
  const int ldst = wave*1024;

  const int S = (lr&7)<<4;
  const int koff0 = ((lg<<4)     ) ^ S;
  const int koff1 = (64 + (lg<<4)) ^ S;
  const int arow = (wm*64 + lr)*128;
  const int brow = (wn*64 + lr)*128;

  f32x4 acc[4][4];
  #pragma unroll
  for (int i=0;i<4;i++)
    #pragma unroll
    for (int j=0;j<4;j++) acc[i][j] = (f32x4){0.f,0.f,0.f,0.f};

  for (int t=0; t<nt; ++t){
    #pragma unroll
    for (int q=0;q<4;q++){
      __builtin_amdgcn_global_load_lds(
        (const __attribute__((address_space(1))) void*)((const char*)Ag + aoff + q*65536 + (size_t)t*128),
        (__attribute__((address_space(3))) void*)((char*)sA + ldst + q*4096), 16, 0, 0);
      __builtin_amdgcn_global_load_lds(
        (const __attribute__((address_space(1))) void*)((const char*)Bq + boff + q*65536 + (size_t)t*128),
        (__attribute__((address_space(3))) void*)((char*)sB + ldst + q*4096), 16, 0, 0);
    }
    __syncthreads();
    {
      bf16x8 a[4], b[4];
      #pragma unroll
      for (int m=0;m<4;m++) a[m] = RD(sA, arow + m*2048 + koff0);
      #pragma unroll
      for (int n=0;n<4;n++) b[n] = RD(sB, brow + n*2048 + koff0);
      #pragma unroll
      for (int m=0;m<4;m++)
        #pragma unroll
        for (int n=0;n<4;n++)
          acc[m][n] = __builtin_amdgcn_mfma_f32_16x16x32_bf16(a[m], b[n], acc[m][n], 0,0,0);
      #pragma unroll
      for (int m=0;m<4;m++) a[m] = RD(sA, arow + m*2048 + koff1);
      #pragma unroll
      for (int n=0;n<4;n++) b[n] = RD(sB, brow + n*2048 + koff1);
      #pragma unroll
      for (int m=0;m<4;m++)
        #pragma unroll
        for (int n=0;n<4;n++)
          acc[m][n] = __builtin_amdgcn_mfma_f32_16x16x32_bf16(a[m], b[n], acc[m][n], 0,0,0);
    }
    __syncthreads();
  }

  #pragma unroll
  for (int mi=0; mi<4; ++mi){
    #pragma unroll
    for (int ni=0; ni<4; ++ni){
      const int col = bn0 + wn*64 + ni*16 + lr;
      const float sc = bscale[col];
      const int rowb = bm0 + wm*64 + mi*16 + lg*4;
      const f32x4 a = acc[mi][ni];
      if (bn0 < 1024){
        #pragma unroll
        for (int r2=0;r2<4;r2++){
          const float val = a[r2]*sc;
          o_r[(size_t)(rowb+r2)*DM + col] = f2bf(1.f/(1.f+expf(-val)));
        }
      } else {
        const int dv = (col - 1024) >> 1;
        #pragma unroll
        for (int r2=0;r2<4;r2++){
          const float val = a[r2]*sc;
          const float pr  = val * __shfl_xor(val, 1);
          if (!(lr & 1))
            o_kv[(size_t)(rowb+r2)*DM + dv] = f2bf(pr);
        }
      }
    }
  }
}

// ---------------- K6: i8 GEMM for the Wo projection (2x MFMA rate, exact i32 acc) ----
#define RD8(base, off) (*(const i32x4*)((const char*)(base) + (off)))

__global__ __launch_bounds__(256, 4)
void gemm_o8(const signed char* __restrict__ Ag, const signed char* __restrict__ Bq,
             const float* __restrict__ bscale, const float* __restrict__ sxr,
             float* __restrict__ o_f)
{
  __shared__ signed char sA[128*128];           // 16KB
  __shared__ signed char sB[128*128];           // 16KB
  const int tid = threadIdx.x, wave = tid>>6, lane = tid&63;
  const int lr = lane&15, lg = lane>>4;
  const int wm = wave>>1, wn = wave&1;
  const int bm0 = blockIdx.x*128, bn0 = blockIdx.y*128;
  constexpr int nt = 8;                         // K = 1024 i8 / 128B

  const int r8   = lane>>3;
  const int scol = ((lane&7)<<4) ^ (r8<<4);
  const size_t aoff = (size_t)(bm0 + wave*8 + r8)*1024 + scol;
  const size_t boff = (size_t)(bn0 + wave*8 + r8)*1024 + scol;
  const int ldst = wave*1024;

  const int S = (lr&7)<<4;
  const int koff0 = ((lg<<4)     ) ^ S;
  const int koff1 = (64 + (lg<<4)) ^ S;
  const int arow = (wm*64 + lr)*128;
  const int brow = (wn*64 + lr)*128;

  i32x4 acc[4][4];
  #pragma unroll
  for (int i=0;i<4;i++)
    #pragma unroll
    for (int j=0;j<4;j++) acc[i][j] = (i32x4){0,0,0,0};

  for (int t=0; t<nt; ++t){
    #pragma unroll
    for (int q=0;q<4;q++){
      __builtin_amdgcn_global_load_lds(
        (const __attribute__((address_space(1))) void*)((const char*)Ag + aoff + q*32768 + (size_t)t*128),
        (__attribute__((address_space(3))) void*)((char*)sA + ldst + q*4096), 16, 0, 0);
      __builtin_amdgcn_global_load_lds(
        (const __attribute__((address_space(1))) void*)((const char*)Bq + boff + q*32768 + (size_t)t*128),
        (__attribute__((address_space(3))) void*)((char*)sB + ldst + q*4096), 16, 0, 0);
    }
    __syncthreads();
    {
      i32x4 a[4], b[4];
      #pragma unroll
      for (int m=0;m<4;m++) a[m] = RD8(sA, arow + m*2048 + koff0);
      #pragma unroll
      for (int n=0;n<4;n++) b[n] = RD8(sB, brow + n*2048 + koff0);
      #pragma unroll
      for (int m=0;m<4;m++)
        #pragma unroll
        for (int n=0;n<4;n++)
          acc[m][n] = __builtin_amdgcn_mfma_i32_16x16x64_i8(a[m], b[n], acc[m][n], 0,0,0);
      #pragma unroll
      for (int m=0;m<4;m++) a[m] = RD8(sA, arow + m*2048 + koff1);
      #pragma unroll
      for (int n=0;n<4;n++) b[n] = RD8(sB, brow + n*2048 + koff1);
      #pragma unroll
      for (int m=0;m<4;m++)
        #pragma unroll
        for (int n=0;n<4;n++)
          acc[m][n] = __builtin_amdgcn_mfma_i32_16x16x64_i8(a[m], b[n], acc[m][n], 0,0,0);
    }
    __syncthreads();
  }

  #pragma unroll
  for (int mi=0; mi<4; ++mi){
    const int rowb = bm0 + wm*64 + mi*16 + lg*4;
    float sx[4];
    #pragma unroll
    for (int r2=0;r2<4;r2++) sx[r2] = sxr[rowb+r2];
    #pragma unroll
    for (int ni=0; ni<4; ++ni){
      const int col = bn0 + wn*64 + ni*16 + lr;
      const float sc = bscale[col];
      const i32x4 a = acc[mi][ni];
      #pragma unroll
      for (int r2=0;r2<4;r2++)
        o_f[(size_t)(rowb+r2)*DM + col] = (float)a[r2] * sx[r2] * sc;
    }
  }
}

// ---------------- K3: per-chunk sums via reciprocal chain (no div/expf per t) -------
// sv = kv * min(rc,1e10) == kv / max(e,1e-10): rc=1/e within ~3e-6 chain drift for
// t<73; both saturate exactly for t>=73 (rc>1e10 -> 1e10; inf*finite=inf -> 1e10).
__global__ __launch_bounds__(256)
void kv_phase1(const u16* __restrict__ kv, const float* __restrict__ decay,
               float* __restrict__ part)
{
  const int c = blockIdx.x & 127, b = blockIdx.x >> 7;
  const int d0 = threadIdx.x*4;
  float rc[4], E1i[4]; f32x4 sum = {0.f,0.f,0.f,0.f};
  #pragma unroll
  for (int j=0;j<4;j++){
    const float dec = 1.f/(1.f+expf(-decay[d0+j]));
    const float ld  = logf(fmaxf(dec, 1e-7f));
    E1i[j] = expf(-ld);
    rc[j]  = expf(-(float)(c*32)*ld);           // 1/e at chunk start (inf ok -> clipped)
  }
  for (int t=c*32; t<c*32+32; ++t){
    const size_t base = ((size_t)(b*4096 + t))*DM + d0;
    const u16x4 p4 = *(const u16x4*)&kv[base];
    #pragma unroll
    for (int j=0;j<4;j++){
      sum[j] += bf2f(p4[j]) * fminf(rc[j], 1e10f);
      rc[j] *= E1i[j];
    }
  }
  *(f32x4*)&part[((size_t)(b*128+c))*DM + d0] = sum;
}

// ---------------- K4: exclusive prefix over 128 chunk sums (16 blocks, 1 d/thread) --
__global__ void chunk_prefix(float* __restrict__ part){
  const int g = blockIdx.x*256 + threadIdx.x;  // 0..4095
  const int b = g >> 10, d = g & 1023;
  float run = 0.f;
  for (int c8=0; c8<128; c8+=8){
    float v[8];
    #pragma unroll
    for (int i=0;i<8;i++)
      v[i] = part[((size_t)(b*128+c8+i))*DM + d];
    #pragma unroll
    for (int i=0;i<8;i++){
      const float tmp = v[i];
      part[((size_t)(b*128+c8+i))*DM + d] = run;
      run += tmp;
    }
  }
}

// ---------------- K5: scan (chained e, rc) + y=r*state + rmsnorm -> i8 yn -----------
__global__ __launch_bounds__(256)
void scan_norm(const u16* __restrict__ kv, const u16* __restrict__ rbuf,
               const float* __restrict__ part, const float* __restrict__ decay,
               const float* __restrict__ lnw, signed char* __restrict__ yn8,
               float* __restrict__ sxr)
{
  const int c = blockIdx.x & 127, b = blockIdx.x >> 7;
  const int tid = threadIdx.x, lane = tid&63, wave = tid>>6;
  const int d0 = tid*4;
  __shared__ float redS[2][4];
  __shared__ float redM[2][4];
  f32x4 run = *(const f32x4*)&part[((size_t)(b*128+c))*DM + d0];
  float lw[4], e[4], E1[4], rc[4], E1i[4];
  #pragma unroll
  for (int j=0;j<4;j++){
    const float dec = 1.f/(1.f+expf(-decay[d0+j]));
    const float ld  = logf(fmaxf(dec, 1e-7f));
    lw[j]  = lnw[d0+j];
    E1[j]  = expf(ld);
    E1i[j] = expf(-ld);
    e[j]   = expf((float)(c*32)*ld);            // underflows to 0 like ref
    rc[j]  = expf(-(float)(c*32)*ld);           // inf ok -> clipped
  }
  for (int t=c*32; t<c*32+32; ++t){
    const size_t base = ((size_t)(b*4096+t))*DM + d0;
    const u16x4 p4 = *(const u16x4*)&kv[base];
    const u16x4 r4 = *(const u16x4*)&rbuf[base];
    float yl[4]; float ss = 0.f, mx = 0.f;
    #pragma unroll
    for (int j=0;j<4;j++){
      run[j] += bf2f(p4[j]) * fminf(rc[j], 1e10f);
      const float st = run[j]*e[j];             // chained e: monotone underflow to 0
      const float y = bf2f(r4[j])*st;
      ss += y*y;
      yl[j] = y*lw[j];
      mx = fmaxf(mx, fabsf(yl[j]));
      rc[j] *= E1i[j];
      e[j]  *= E1[j];
    }
    #pragma unroll
    for (int off=32; off; off>>=1){
      ss += __shfl_down(ss, off);
      mx  = fmaxf(mx, __shfl_down(mx, off));
    }
    if (lane==0){ redS[t&1][wave] = ss; redM[t&1][wave] = mx; }
    __builtin_amdgcn_s_barrier();
    const float tot = (redS[t&1][0]+redS[t&1][1])+(redS[t&1][2]+redS[t&1][3]);
    const float m1  = fmaxf(fmaxf(redM[t&1][0],redM[t&1][1]),
                            fmaxf(redM[t&1][2],redM[t&1][3]));
    const float rs  = 1.f/sqrtf(tot*(1.f/1024.f) + 1e-6f);
    const float m1s = fmaxf(m1, 1e-30f);
    const float qk  = 127.f/m1s;
    if (tid==0) sxr[b*4096+t] = m1s*rs*(1.f/127.f);
    unsigned int p = 0;
    #pragma unroll
    for (int j=0;j<4;j++){
      int q = (int)rintf(yl[j]*qk);
      q = q>127?127:(q<-127?-127:q);
      p |= ((unsigned)(q&0xFF)) << (8*j);
    }
    *(unsigned int*)&yn8[base] = p;
  }
}

extern "C" void kernel_launch(void* const* d_in, const int* in_sizes, int n_in,
                              void* d_out, int out_size, void* d_ws, size_t ws_size,
                              hipStream_t stream)
{
  (void)in_sizes; (void)n_in; (void)out_size; (void)ws_size;
  const float* x    = (const float*)d_in[0];
  const float* Wr   = (const float*)d_in[1];
  const float* Wk   = (const float*)d_in[2];
  const float* Wv   = (const float*)d_in[3];
  const float* Wo   = (const float*)d_in[4];
  const float* dec  = (const float*)d_in[5];
  const float* lnw  = (const float*)d_in[6];

  // layout: wq 6MB | wq8 1MB | wsc 16KB | rbuf 33.5MB | kvbuf 33.5MB | part 2MB |
  //         xb 33.5MB | yn8 16.8MB | sxr 64KB
  char* ws = (char*)d_ws;
  u16*         wq    = (u16*)(ws + 0);
  signed char* wq8   = (signed char*)(ws + 6291456);
  float*       wsc   = (float*)(ws + 7340032);
  u16*         rbuf  = (u16*)(ws + 7356416);
  u16*         kvbuf = (u16*)(ws + 40910848);
  float*       part  = (float*)(ws + 74465280);
  u16*         xb    = (u16*)(ws + 76562432);
  signed char* yn8   = (signed char*)(ws + 110116864);
  float*       sxr   = (float*)(ws + 126894080);   // ends 126,959,616

  init_pack<<<17408, 256, 0, stream>>>(Wr, Wk, Wv, Wo, x, wq, wq8, wsc, xb);
  gemm_rkv<<<dim3(128,24), 256, 0, stream>>>(xb, wq, wsc, rbuf, kvbuf);
  kv_phase1<<<512, 256, 0, stream>>>(kvbuf, dec, part);
  chunk_prefix<<<16, 256, 0, stream>>>(part);
  scan_norm<<<512, 256, 0, stream>>>(kvbuf, rbuf, part, dec, lnw, yn8, sxr);
  gemm_o8<<<dim3(128,8), 256, 0, stream>>>(yn8, wq8, wsc + 3072, sxr, (float*)d_out);
}